// Round 9
// baseline (583.833 us; speedup 1.0000x reference)
//
#include <hip/hip_runtime.h>
#include <math.h>

#define B_ 2
#define N_ 6
#define D_ 59
#define FH 32
#define FW 88
#define C_ 80
#define NX 360
#define NY 360
#define P_PER_B (N_*D_*FH*FW)     // 996,864
#define NPTS (B_*P_PER_B)         // 1,993,728
#define NCELL (NX*NY)             // 129,600
#define NC (B_*NCELL)             // 259,200 cells
#define NCP (254*1024)            // 260,096 (cnt zero range, int4-aligned)
#define OUT4 (B_*C_*NCELL/4)      // 5,184,000 float4 in out
#define SMAX 48                   // cells <= SMAX points -> thread-mode
#define CHK 192                   // points per wave-chunk (divisible by 3)
#define MAXCHK (NC + NPTS/CHK)
#define NBLOCKS 1024
#define NTHREADS (NBLOCKS*256)    // 262,144

// Static device scratch; every read location rewritten each launch (replay safe).
__device__ float g_inv[B_*N_*16];
__device__ int   g_code[NPTS];
__device__ __align__(16) int g_cnt[NCP];
__device__ int   g_escan[NTHREADS];
__device__ int   g_bsum[NBLOCKS];
__device__ int   g_offs[NC+1];
__device__ int   g_cur[NC];
__device__ __align__(16) int g_plist[NPTS];
__device__ int   g_nS;
__device__ int   g_nB;
__device__ int2  g_cellS[NC];
__device__ int2  g_chunkB[MAXCHK];
// grid barrier state (monotone generation; zero-init at module load, grows
// across launches/replays -> no reset needed, deterministic behavior)
__device__ int   g_arrive[NBLOCKS];
__device__ int   g_genv;

__device__ __forceinline__ void gridbar(int gen) {
  __syncthreads();
  if (threadIdx.x == 0)
    __hip_atomic_store(&g_arrive[blockIdx.x], gen, __ATOMIC_RELEASE, __HIP_MEMORY_SCOPE_AGENT);
  if (blockIdx.x == 0) {
    for (int j = threadIdx.x; j < NBLOCKS; j += 256)
      while (__hip_atomic_load(&g_arrive[j], __ATOMIC_ACQUIRE, __HIP_MEMORY_SCOPE_AGENT) < gen)
        __builtin_amdgcn_s_sleep(1);
    __syncthreads();
    if (threadIdx.x == 0)
      __hip_atomic_store(&g_genv, gen, __ATOMIC_RELEASE, __HIP_MEMORY_SCOPE_AGENT);
  }
  if (threadIdx.x == 0)
    while (__hip_atomic_load(&g_genv, __ATOMIC_ACQUIRE, __HIP_MEMORY_SCOPE_AGENT) < gen)
      __builtin_amdgcn_s_sleep(1);
  __syncthreads();
}

__device__ __forceinline__ int geom_code(int p, const float* itrans, const float* iscale) {
#pragma clang fp contract(off)
  int b  = p / P_PER_B;
  int r  = p - b*P_PER_B;
  int n  = r / (D_*FH*FW);
  int r2 = r - n*(D_*FH*FW);
  int d  = r2 / (FH*FW);
  int r3 = r2 - d*(FH*FW);
  int h  = r3 / FW;
  int w  = r3 - h*FW;
  int bn = b*N_ + n;

  float xw = (float)((double)w * (703.0/87.0));   // np.linspace in f64, rounded
  float yh = (float)((double)h * (255.0/31.0));
  float dd = (float)(d + 1);                      // ds = 1..59

  float t0 = itrans[bn*3+0], t1 = itrans[bn*3+1], t2 = itrans[bn*3+2];
  float s  = iscale[bn];

  float px = xw + t0, py = yh + t1, pd = dd + t2;
  float x0 = px / s, x1 = py / s;
  float p0 = x0*pd, p1 = x1*pd, p2 = pd;

  const float* iv = &g_inv[bn*16];
  float gx = ((iv[0]*p0 + iv[1]*p1) + iv[2]*p2)  + iv[3]*1.0f;
  float gy = ((iv[4]*p0 + iv[5]*p1) + iv[6]*p2)  + iv[7]*1.0f;
  float gz = ((iv[8]*p0 + iv[9]*p1) + iv[10]*p2) + iv[11]*1.0f;

  int vx = (int)((gx + 54.0f) / 0.3f);            // trunc == astype(int32)
  int vy = (int)((gy + 54.0f) / 0.3f);
  int vz = (int)((gz + 10.0f) / 20.0f);

  bool ok = (vx>=0) & (vx<NX) & (vy>=0) & (vy<NY) & (vz>=0) & (vz<1);
  return ok ? (b*NCELL + vx*NY + vy) : -1;
}

__global__ void __launch_bounds__(256, 4) k_mega(const float* __restrict__ feats,
                                                 const float* __restrict__ itrans,
                                                 const float* __restrict__ iscale,
                                                 const float* __restrict__ l2i,
                                                 float* __restrict__ out) {
  __shared__ int sd[257];
  int tid = threadIdx.x, bid = blockIdx.x;
  int gid = bid*256 + tid;
  int lane = tid & 63;
  int base = __hip_atomic_load(&g_genv, __ATOMIC_RELAXED, __HIP_MEMORY_SCOPE_AGENT);
  const float4 z4 = make_float4(0.f,0.f,0.f,0.f);

  // ================= P0: zero cnt + counters + inverse + out-zero (part 1)
  if (gid < NCP/4) ((int4*)g_cnt)[gid] = make_int4(0,0,0,0);
  if (gid == NCP/4) { g_nS = 0; g_nB = 0; }
  if (bid == 300 && tid < B_*N_) {
    int m = tid;
    double a[4][4], inv[4][4];
    for (int r=0;r<4;r++) for (int j=0;j<4;j++){
      a[r][j] = (double)l2i[m*16+r*4+j];
      inv[r][j] = (r==j)?1.0:0.0;
    }
    for (int k=0;k<4;k++){
      int p=k; double mx=fabs(a[k][k]);
      for (int r=k+1;r<4;r++){ double v=fabs(a[r][k]); if (v>mx){mx=v;p=r;} }
      if (p!=k){
        for (int j=0;j<4;j++){
          double t=a[k][j]; a[k][j]=a[p][j]; a[p][j]=t;
          t=inv[k][j]; inv[k][j]=inv[p][j]; inv[p][j]=t;
        }
      }
      double pi = 1.0/a[k][k];
      for (int j=0;j<4;j++){ a[k][j]*=pi; inv[k][j]*=pi; }
      for (int r=0;r<4;r++) if (r!=k){
        double f=a[r][k];
        for (int j=0;j<4;j++){ a[r][j]-=f*a[k][j]; inv[r][j]-=f*inv[k][j]; }
      }
    }
    for (int r=0;r<4;r++) for (int j=0;j<4;j++)
      g_inv[m*16+r*4+j] = (float)inv[r][j];
  }
  #pragma unroll
  for (int s=0; s<10; ++s)
    ((float4*)out)[gid + s*NTHREADS] = z4;        // 2,621,440 < OUT4, no guard
  gridbar(base+1);

  // ================= P1: geometry + counts (+ out-zero part 2)
  #pragma unroll 1
  for (int s=0; s<8; ++s) {
    int p = gid + s*NTHREADS;
    int code = (p < NPTS) ? geom_code(p, itrans, iscale) : -1;
    if (p < NPTS) g_code[p] = code;
    int prev = __shfl_up(code, 1);
    bool leader = (lane == 0) || (code != prev);
    unsigned long long m = __ballot(leader);
    if (leader && code >= 0) {
      unsigned long long above = (lane < 63) ? (m >> (lane+1)) : 0ULL;
      int len = above ? __ffsll(above) : (64 - lane);
      atomicAdd(&g_cnt[code], len);
    }
  }
  #pragma unroll 1
  for (int s=10; s<20; ++s) {
    int u = gid + s*NTHREADS;
    if (u < OUT4) ((float4*)out)[u] = z4;
  }
  gridbar(base+2);

  // ================= P2: per-cell block scan (256-wide)
  {
    int v = (gid < NC) ? g_cnt[gid] : 0;
    sd[tid] = v;
    for (int off=1; off<256; off<<=1) {
      __syncthreads();
      int x = (tid >= off) ? sd[tid-off] : 0;
      __syncthreads();
      sd[tid] += x;
    }
    g_escan[gid] = sd[tid] - v;
    if (tid == 255) g_bsum[bid] = sd[255];
  }
  gridbar(base+3);

  // ================= P3: block-prefix reduce + offsets + classify
  {
    int hi = (bid == 0) ? NBLOCKS : bid;
    int part = 0;
    for (int j = tid; j < hi; j += 256) part += g_bsum[j];
    sd[tid] = part;
    for (int o = 128; o >= 1; o >>= 1) {
      __syncthreads();
      if (tid < o) sd[tid] += sd[tid+o];
    }
    __syncthreads();
    int bpre = (bid == 0) ? 0 : sd[0];
    if (bid == 0 && tid == 0) g_offs[NC] = sd[0];

    bool inb = (gid < NC);
    int o = 0, len = 0;
    if (inb) {
      o = g_escan[gid] + bpre;
      g_offs[gid] = o;
      g_cur[gid]  = o;
      len = g_cnt[gid];
    }
    bool isS = inb && (len > 0) && (len <= SMAX);
    unsigned long long m = __ballot(isS);
    if (m) {
      int ldr = __ffsll((long long)m) - 1;
      int cbase = 0;
      if (lane == ldr) cbase = atomicAdd(&g_nS, (int)__popcll(m));
      cbase = __shfl(cbase, ldr);
      if (isS) {
        int rank = __popcll(m & ((1ULL << lane) - 1ULL));
        g_cellS[cbase + rank] = make_int2(gid, o);
      }
    }
    if (inb && len > SMAX) {
      int nch = (len + CHK - 1) / CHK;
      int cbase = atomicAdd(&g_nB, nch);
      for (int k = 0; k < nch; ++k)
        g_chunkB[cbase + k] = make_int2(gid, o + k*CHK);
    }
  }
  gridbar(base+4);

  // ================= P4: fill cell-sorted point list
  #pragma unroll 1
  for (int s=0; s<8; ++s) {
    int p = gid + s*NTHREADS;
    int code = (p < NPTS) ? g_code[p] : -1;
    int prev = __shfl_up(code, 1);
    bool leader = (lane == 0) || (code != prev);
    unsigned long long m = __ballot(leader);
    unsigned long long mask_le = (lane==63) ? ~0ULL : ((1ULL << (lane+1)) - 1ULL);
    int leaderLane = 63 - __clzll(m & mask_le);
    int pos0 = 0;
    if (leader && code >= 0) {
      unsigned long long above = (lane < 63) ? (m >> (lane+1)) : 0ULL;
      int len = above ? __ffsll(above) : (64 - lane);
      pos0 = atomicAdd(&g_cur[code], len);
    }
    pos0 = __shfl(pos0, leaderLane);
    if (code >= 0) g_plist[pos0 + (lane - leaderLane)] = p;
  }
  gridbar(base+5);

  // ================= P5: gather (wave-mode big chunks, then thread-mode)
  {
    const float4* f4 = (const float4*)feats;
    int nB = g_nB;
    int wid = gid >> 6;
    int grp = lane/20;
    int c4w = lane - grp*20;
    bool act = lane < 60;
    for (int it = wid; it < nB; it += NTHREADS/64) {
      int2 e = g_chunkB[it];
      int c = e.x, s0 = e.y;
      int o0 = g_offs[c], o1 = g_offs[c+1];
      int s1 = min(s0 + CHK, o1);
      float ax=0.f, ay=0.f, az=0.f, aw=0.f;
      if (act) {
        int j = s0 + grp;
        for (; j + 9 < s1; j += 12) {
          int p0=g_plist[j], p1=g_plist[j+3], p2=g_plist[j+6], p3=g_plist[j+9];
          float4 v0=f4[(size_t)p0*20+c4w], v1=f4[(size_t)p1*20+c4w];
          float4 v2=f4[(size_t)p2*20+c4w], v3=f4[(size_t)p3*20+c4w];
          ax += v0.x+v1.x+v2.x+v3.x;
          ay += v0.y+v1.y+v2.y+v3.y;
          az += v0.z+v1.z+v2.z+v3.z;
          aw += v0.w+v1.w+v2.w+v3.w;
        }
        for (; j < s1; j += 3) {
          int p = g_plist[j];
          float4 v = f4[(size_t)p*20+c4w];
          ax+=v.x; ay+=v.y; az+=v.z; aw+=v.w;
        }
      }
      float bx=__shfl(ax,c4w+20), by=__shfl(ay,c4w+20), bz=__shfl(az,c4w+20), bw=__shfl(aw,c4w+20);
      float cx=__shfl(ax,c4w+40), cy=__shfl(ay,c4w+40), cz=__shfl(az,c4w+40), cw=__shfl(aw,c4w+40);
      if (lane < 20) {
        ax += bx + cx; ay += by + cy; az += bz + cz; aw += bw + cw;
        int b = c / NCELL;
        int xy = c - b*NCELL;
        float* dst = out + (size_t)(b*C_ + c4w*4)*NCELL + xy;
        if (o1 - o0 <= CHK) {
          dst[0]       = ax;
          dst[NCELL]   = ay;
          dst[2*NCELL] = az;
          dst[3*NCELL] = aw;
        } else {
          atomicAdd(dst,         ax);
          atomicAdd(dst+NCELL,   ay);
          atomicAdd(dst+2*NCELL, az);
          atomicAdd(dst+3*NCELL, aw);
        }
      }
    }

    int nS = g_nS;
    int tot = nS*20;
    for (int i = gid; i < tot; i += NTHREADS) {
      int ci = i/20;
      int c4 = i - ci*20;
      int2 e = g_cellS[ci];
      int c = e.x, o0 = e.y;
      int o1 = g_offs[c+1];
      float ax=0.f, ay=0.f, az=0.f, aw=0.f;
      int j = o0;
      for (; j + 8 <= o1; j += 8) {
        int p0=g_plist[j],   p1=g_plist[j+1], p2=g_plist[j+2], p3=g_plist[j+3];
        int p4=g_plist[j+4], p5=g_plist[j+5], p6=g_plist[j+6], p7=g_plist[j+7];
        float4 v0=f4[(size_t)p0*20+c4], v1=f4[(size_t)p1*20+c4];
        float4 v2=f4[(size_t)p2*20+c4], v3=f4[(size_t)p3*20+c4];
        float4 v4=f4[(size_t)p4*20+c4], v5=f4[(size_t)p5*20+c4];
        float4 v6=f4[(size_t)p6*20+c4], v7=f4[(size_t)p7*20+c4];
        ax += (v0.x+v1.x)+(v2.x+v3.x)+(v4.x+v5.x)+(v6.x+v7.x);
        ay += (v0.y+v1.y)+(v2.y+v3.y)+(v4.y+v5.y)+(v6.y+v7.y);
        az += (v0.z+v1.z)+(v2.z+v3.z)+(v4.z+v5.z)+(v6.z+v7.z);
        aw += (v0.w+v1.w)+(v2.w+v3.w)+(v4.w+v5.w)+(v6.w+v7.w);
      }
      for (; j < o1; ++j) {
        int p = g_plist[j];
        float4 v = f4[(size_t)p*20+c4];
        ax+=v.x; ay+=v.y; az+=v.z; aw+=v.w;
      }
      int b = c / NCELL;
      int xy = c - b*NCELL;
      float* dst = out + (size_t)(b*C_ + c4*4)*NCELL + xy;
      dst[0]       = ax;
      dst[NCELL]   = ay;
      dst[2*NCELL] = az;
      dst[3*NCELL] = aw;
    }
  }
}

extern "C" void kernel_launch(void* const* d_in, const int* in_sizes, int n_in,
                              void* d_out, int out_size, void* d_ws, size_t ws_size,
                              hipStream_t stream) {
  const float* feats  = (const float*)d_in[0];
  const float* itrans = (const float*)d_in[1];
  const float* iscale = (const float*)d_in[2];
  const float* l2i    = (const float*)d_in[3];
  float* out = (float*)d_out;

  k_mega<<<NBLOCKS, 256, 0, stream>>>(feats, itrans, iscale, l2i, out);
}

// Round 10
// 133.026 us; speedup vs baseline: 4.3889x; 4.3889x over previous
//
#include <hip/hip_runtime.h>
#include <math.h>

#define B_ 2
#define N_ 6
#define D_ 59
#define FH 32
#define FW 88
#define C_ 80
#define NX 360
#define NY 360
#define P_PER_B (N_*D_*FH*FW)     // 996,864
#define NPTS (B_*P_PER_B)         // 1,993,728 = 7788*256
#define NCELL (NX*NY)             // 129,600
#define NC (B_*NCELL)             // 259,200 cells
#define NBLK 254
#define NCP (NBLK*1024)           // 260,096 (int4-aligned zero range)
#define OUT4 (B_*C_*NCELL/4)      // 5,184,000 float4 in out
#define SMAX 48                   // cells <= SMAX points -> thread-mode
#define CHK 192                   // points per wave-chunk (divisible by 3)
#define MAXCHK (NC + NPTS/CHK)
#define TOTBLK 2048
#define BBLK 512
#define SBLK (TOTBLK - BBLK)

// Static device scratch. Self-cleaning invariant: g_cnt/g_nS/g_nB are zero at
// every launch entry (BSS zero-init for launch #1; k_fill re-zeroes them each
// launch after their last read). Everything else is rewritten before read.
__device__ int   g_code[NPTS];
__device__ __align__(16) int g_cnt[NCP];
__device__ int   g_escan[NCP];
__device__ int   g_bsum[NBLK];
__device__ int   g_offs[NC+1];
__device__ int   g_cur[NC];
__device__ __align__(16) int g_plist[NPTS];
__device__ int   g_nS, g_nB;       // appended by scanC; zeroed by fill
__device__ int   g_nS2, g_nB2;     // snapshots read by gather
__device__ int2  g_cellS[NC];
__device__ int2  g_chunkB[MAXCHK];

// ---- 1) geom fused with out-zero + per-block redundant matrix inverse
__global__ void k_geomz(const float* __restrict__ itrans,
                        const float* __restrict__ iscale,
                        const float* __restrict__ l2i,
                        float* __restrict__ out) {
#pragma clang fp contract(off)
  __shared__ float sinv[B_*N_*16];
  int tid = threadIdx.x;
  int p = blockIdx.x*256 + tid;                    // grid exact: NPTS/256

  // out-zero (fire-and-forget stores; overlap the inverse + geom below)
  const float4 z4 = make_float4(0.f,0.f,0.f,0.f);
  #pragma unroll
  for (int s=0; s<3; ++s) {
    int u = p + s*NPTS;
    if (u < OUT4) ((float4*)out)[u] = z4;
  }

  // per-block redundant inverse of the 12 lidar2img matrices (f64 GJ, pivot)
  if (tid < B_*N_) {
    int m = tid;
    double a[4][4], inv[4][4];
    for (int r=0;r<4;r++) for (int j=0;j<4;j++){
      a[r][j] = (double)l2i[m*16+r*4+j];
      inv[r][j] = (r==j)?1.0:0.0;
    }
    for (int k=0;k<4;k++){
      int pv=k; double mx=fabs(a[k][k]);
      for (int r=k+1;r<4;r++){ double v=fabs(a[r][k]); if (v>mx){mx=v;pv=r;} }
      if (pv!=k){
        for (int j=0;j<4;j++){
          double t=a[k][j]; a[k][j]=a[pv][j]; a[pv][j]=t;
          t=inv[k][j]; inv[k][j]=inv[pv][j]; inv[pv][j]=t;
        }
      }
      double pi = 1.0/a[k][k];
      for (int j=0;j<4;j++){ a[k][j]*=pi; inv[k][j]*=pi; }
      for (int r=0;r<4;r++) if (r!=k){
        double f=a[r][k];
        for (int j=0;j<4;j++){ a[r][j]-=f*a[k][j]; inv[r][j]-=f*inv[k][j]; }
      }
    }
    for (int r=0;r<4;r++) for (int j=0;j<4;j++)
      sinv[m*16+r*4+j] = (float)inv[r][j];
  }
  __syncthreads();

  // geometry (identical math to R8; iv from LDS)
  int b  = p / P_PER_B;
  int r  = p - b*P_PER_B;
  int n  = r / (D_*FH*FW);
  int r2 = r - n*(D_*FH*FW);
  int d  = r2 / (FH*FW);
  int r3 = r2 - d*(FH*FW);
  int h  = r3 / FW;
  int w  = r3 - h*FW;
  int bn = b*N_ + n;

  float xw = (float)((double)w * (703.0/87.0));    // np.linspace in f64, rounded
  float yh = (float)((double)h * (255.0/31.0));
  float dd = (float)(d + 1);                       // ds = 1..59

  float t0 = itrans[bn*3+0], t1 = itrans[bn*3+1], t2 = itrans[bn*3+2];
  float s  = iscale[bn];

  float px = xw + t0, py = yh + t1, pd = dd + t2;
  float x0 = px / s, x1 = py / s;
  float p0 = x0*pd, p1 = x1*pd, p2 = pd;

  const float* iv = &sinv[bn*16];
  float gx = ((iv[0]*p0 + iv[1]*p1) + iv[2]*p2)  + iv[3]*1.0f;
  float gy = ((iv[4]*p0 + iv[5]*p1) + iv[6]*p2)  + iv[7]*1.0f;
  float gz = ((iv[8]*p0 + iv[9]*p1) + iv[10]*p2) + iv[11]*1.0f;

  int vx = (int)((gx + 54.0f) / 0.3f);             // trunc == astype(int32)
  int vy = (int)((gy + 54.0f) / 0.3f);
  int vz = (int)((gz + 10.0f) / 20.0f);

  bool ok = (vx>=0) & (vx<NX) & (vy>=0) & (vy<NY) & (vz>=0) & (vz<1);
  int code = ok ? (b*NCELL + vx*NY + vy) : -1;
  g_code[p] = code;

  int lane = tid & 63;
  int prev = __shfl_up(code, 1);
  bool leader = (lane == 0) || (code != prev);
  unsigned long long m = __ballot(leader);
  if (leader && code >= 0) {
    unsigned long long above = (lane < 63) ? (m >> (lane+1)) : 0ULL;
    int len = above ? __ffsll(above) : (64 - lane);
    atomicAdd(&g_cnt[code], len);
  }
}

// ---- 2) per-block exclusive scan (1024) over counts
__global__ void __launch_bounds__(1024) k_scanA() {
  __shared__ int sd[1024];
  int t = threadIdx.x;
  int i = blockIdx.x*1024 + t;
  int v = g_cnt[i];
  sd[t] = v;
  for (int off=1; off<1024; off<<=1) {
    __syncthreads();
    int x = (t >= off) ? sd[t-off] : 0;
    __syncthreads();
    sd[t] += x;
  }
  g_escan[i] = sd[t] - v;
  if (t == 1023) g_bsum[blockIdx.x] = sd[1023];
}

// ---- 3) fused: redundant scan of 254 block sums + offsets + classify
__global__ void __launch_bounds__(1024) k_scanC() {
  __shared__ int sb[256];
  int t = threadIdx.x, bid = blockIdx.x;
  if (t < 256) sb[t] = (t < NBLK) ? g_bsum[t] : 0;
  for (int off=1; off<256; off<<=1) {
    __syncthreads();
    int x = 0;
    if (t >= off && t < 256) x = sb[t-off];
    __syncthreads();
    if (t < 256) sb[t] += x;
  }
  __syncthreads();
  int bpre = (bid > 0) ? sb[bid-1] : 0;
  if (bid == 0 && t == 0) g_offs[NC] = sb[NBLK-1]; // total valid count

  int i = bid*1024 + t;
  bool inb = (i < NC);
  int o = 0, len = 0;
  if (inb) {
    o = g_escan[i] + bpre;
    g_offs[i] = o;
    g_cur[i]  = o;
    len = g_cnt[i];
  }
  int lane = t & 63;
  bool isS = inb && (len > 0) && (len <= SMAX);
  unsigned long long m = __ballot(isS);
  if (m) {
    int ldr = __ffsll((long long)m) - 1;
    int base = 0;
    if (lane == ldr) base = atomicAdd(&g_nS, (int)__popcll(m));
    base = __shfl(base, ldr);
    if (isS) {
      int rank = __popcll(m & ((1ULL << lane) - 1ULL));
      g_cellS[base + rank] = make_int2(i, o);
    }
  }
  if (inb && len > SMAX) {
    int nch = (len + CHK - 1) / CHK;
    int base = atomicAdd(&g_nB, nch);
    for (int k = 0; k < nch; ++k)
      g_chunkB[base + k] = make_int2(i, o + k*CHK);
  }
}

// ---- 4) fill cell-sorted point list + self-clean cnt/nS/nB for next launch
__global__ void k_fill() {
  int gid = blockIdx.x*256 + threadIdx.x;          // grid exact: NPTS/256
  if (gid < NCP/4) ((int4*)g_cnt)[gid] = make_int4(0,0,0,0);
  if (gid == 0) { g_nS2 = g_nS; g_nB2 = g_nB; g_nS = 0; g_nB = 0; }

  int code = g_code[gid];
  int lane = threadIdx.x & 63;
  int prev = __shfl_up(code, 1);
  bool leader = (lane == 0) || (code != prev);
  unsigned long long m = __ballot(leader);
  unsigned long long mask_le = (lane==63) ? ~0ULL : ((1ULL << (lane+1)) - 1ULL);
  int leaderLane = 63 - __clzll(m & mask_le);
  int pos0 = 0;
  if (leader && code >= 0) {
    unsigned long long above = (lane < 63) ? (m >> (lane+1)) : 0ULL;
    int len = above ? __ffsll(above) : (64 - lane);
    pos0 = atomicAdd(&g_cur[code], len);
  }
  pos0 = __shfl(pos0, leaderLane);
  if (code >= 0) g_plist[pos0 + (lane - leaderLane)] = gid;
}

// ---- 5) gather: cell-per-worker (wave-mode big chunks + thread-mode small)
__global__ void __launch_bounds__(256) k_gather(const float* __restrict__ feats,
                                                float* __restrict__ out) {
  const float4* f4 = (const float4*)feats;
  if (blockIdx.x < BBLK) {
    int nB = g_nB2;
    int lane = threadIdx.x & 63;
    int wid = blockIdx.x*4 + (threadIdx.x >> 6);
    int grp = lane/20;
    int c4 = lane - grp*20;
    bool act = lane < 60;
    for (int it = wid; it < nB; it += BBLK*4) {
      int2 e = g_chunkB[it];
      int c = e.x, s0 = e.y;
      int o0 = g_offs[c], o1 = g_offs[c+1];
      int s1 = min(s0 + CHK, o1);
      float ax=0.f, ay=0.f, az=0.f, aw=0.f;
      if (act) {
        int j = s0 + grp;
        for (; j + 9 < s1; j += 12) {
          int p0=g_plist[j], p1=g_plist[j+3], p2=g_plist[j+6], p3=g_plist[j+9];
          float4 v0=f4[(size_t)p0*20+c4], v1=f4[(size_t)p1*20+c4];
          float4 v2=f4[(size_t)p2*20+c4], v3=f4[(size_t)p3*20+c4];
          ax += v0.x+v1.x+v2.x+v3.x;
          ay += v0.y+v1.y+v2.y+v3.y;
          az += v0.z+v1.z+v2.z+v3.z;
          aw += v0.w+v1.w+v2.w+v3.w;
        }
        for (; j < s1; j += 3) {
          int p = g_plist[j];
          float4 v = f4[(size_t)p*20+c4];
          ax+=v.x; ay+=v.y; az+=v.z; aw+=v.w;
        }
      }
      float bx=__shfl(ax,c4+20), by=__shfl(ay,c4+20), bz=__shfl(az,c4+20), bw=__shfl(aw,c4+20);
      float cx=__shfl(ax,c4+40), cy=__shfl(ay,c4+40), cz=__shfl(az,c4+40), cw=__shfl(aw,c4+40);
      if (lane < 20) {
        ax += bx + cx; ay += by + cy; az += bz + cz; aw += bw + cw;
        int b = c / NCELL;
        int xy = c - b*NCELL;
        float* dst = out + (size_t)(b*C_ + c4*4)*NCELL + xy;
        if (o1 - o0 <= CHK) {                      // sole chunk -> exclusive
          dst[0]       = ax;
          dst[NCELL]   = ay;
          dst[2*NCELL] = az;
          dst[3*NCELL] = aw;
        } else {                                   // dst zeroed by k_geomz
          atomicAdd(dst,         ax);
          atomicAdd(dst+NCELL,   ay);
          atomicAdd(dst+2*NCELL, az);
          atomicAdd(dst+3*NCELL, aw);
        }
      }
    }
  } else {
    int nS = g_nS2;
    int tot = nS*20;
    for (int i = (blockIdx.x - BBLK)*256 + threadIdx.x; i < tot; i += SBLK*256) {
      int ci = i/20;
      int c4 = i - ci*20;
      int2 e = g_cellS[ci];
      int c = e.x, o0 = e.y;
      int o1 = g_offs[c+1];
      float ax=0.f, ay=0.f, az=0.f, aw=0.f;
      int j = o0;
      for (; j + 8 <= o1; j += 8) {
        int p0=g_plist[j],   p1=g_plist[j+1], p2=g_plist[j+2], p3=g_plist[j+3];
        int p4=g_plist[j+4], p5=g_plist[j+5], p6=g_plist[j+6], p7=g_plist[j+7];
        float4 v0=f4[(size_t)p0*20+c4], v1=f4[(size_t)p1*20+c4];
        float4 v2=f4[(size_t)p2*20+c4], v3=f4[(size_t)p3*20+c4];
        float4 v4=f4[(size_t)p4*20+c4], v5=f4[(size_t)p5*20+c4];
        float4 v6=f4[(size_t)p6*20+c4], v7=f4[(size_t)p7*20+c4];
        ax += (v0.x+v1.x)+(v2.x+v3.x)+(v4.x+v5.x)+(v6.x+v7.x);
        ay += (v0.y+v1.y)+(v2.y+v3.y)+(v4.y+v5.y)+(v6.y+v7.y);
        az += (v0.z+v1.z)+(v2.z+v3.z)+(v4.z+v5.z)+(v6.z+v7.z);
        aw += (v0.w+v1.w)+(v2.w+v3.w)+(v4.w+v5.w)+(v6.w+v7.w);
      }
      for (; j < o1; ++j) {
        int p = g_plist[j];
        float4 v = f4[(size_t)p*20+c4];
        ax+=v.x; ay+=v.y; az+=v.z; aw+=v.w;
      }
      int b = c / NCELL;
      int xy = c - b*NCELL;
      float* dst = out + (size_t)(b*C_ + c4*4)*NCELL + xy;
      dst[0]       = ax;
      dst[NCELL]   = ay;
      dst[2*NCELL] = az;
      dst[3*NCELL] = aw;
    }
  }
}

extern "C" void kernel_launch(void* const* d_in, const int* in_sizes, int n_in,
                              void* d_out, int out_size, void* d_ws, size_t ws_size,
                              hipStream_t stream) {
  const float* feats  = (const float*)d_in[0];
  const float* itrans = (const float*)d_in[1];
  const float* iscale = (const float*)d_in[2];
  const float* l2i    = (const float*)d_in[3];
  float* out = (float*)d_out;

  k_geomz<<<NPTS/256, 256, 0, stream>>>(itrans, iscale, l2i, out); // 7,788 blocks
  k_scanA<<<NBLK, 1024, 0, stream>>>();
  k_scanC<<<NBLK, 1024, 0, stream>>>();
  k_fill<<<NPTS/256, 256, 0, stream>>>();                          // 7,788 blocks
  k_gather<<<TOTBLK, 256, 0, stream>>>(feats, out);                // 2,048 blocks
}

// Round 11
// 127.627 us; speedup vs baseline: 4.5745x; 1.0423x over previous
//
#include <hip/hip_runtime.h>
#include <math.h>

#define B_ 2
#define N_ 6
#define D_ 59
#define FH 32
#define FW 88
#define C_ 80
#define NX 360
#define NY 360
#define P_PER_B (N_*D_*FH*FW)     // 996,864
#define NPTS (B_*P_PER_B)         // 1,993,728 = 7788*256
#define NCELL (NX*NY)             // 129,600
#define NC (B_*NCELL)             // 259,200 cells
#define NBLK 254
#define NCP (NBLK*1024)           // 260,096 (int4-aligned zero range)
#define OUT4 (B_*C_*NCELL/4)      // 5,184,000 float4 in out
#define SMAX 32                   // cells <= SMAX points -> thread-mode
#define CHK 96                    // points per wave-chunk (divisible by 3)
#define MAXCHK (NC/4 + NPTS/CHK)
#define TOTBLK 2048
#define BBLK 512
#define SBLK (TOTBLK - BBLK)

// Static device scratch. Self-cleaning invariant: g_cnt/g_nS/g_nB/g_total are
// zero at every launch entry (BSS zero-init for launch #1; k_fill re-zeroes
// them each launch after their last read). Everything else is written before
// read within a launch.
__device__ int   g_code[NPTS];
__device__ __align__(16) int g_cnt[NCP];
__device__ int   g_cur[NC];
__device__ __align__(16) int g_plist[NPTS];
__device__ int   g_total;
__device__ int   g_nS, g_nB;       // appended by alloc; zeroed by fill
__device__ int   g_nS2, g_nB2;     // snapshots read by gather
__device__ int2  g_cellS[NC];      // {cell | len<<18, o0}
__device__ int2  g_chunkB[MAXCHK]; // {cell | clen<<18 | sole<<30, s0}

// ---- 1) geom fused with out-zero + per-block redundant matrix inverse
__global__ void k_geomz(const float* __restrict__ itrans,
                        const float* __restrict__ iscale,
                        const float* __restrict__ l2i,
                        float* __restrict__ out) {
#pragma clang fp contract(off)
  __shared__ float sinv[B_*N_*16];
  int tid = threadIdx.x;
  int p = blockIdx.x*256 + tid;                    // grid exact: NPTS/256

  // out-zero (fire-and-forget stores; overlap the inverse + geom below)
  const float4 z4 = make_float4(0.f,0.f,0.f,0.f);
  #pragma unroll
  for (int s=0; s<3; ++s) {
    int u = p + s*NPTS;
    if (u < OUT4) ((float4*)out)[u] = z4;
  }

  // per-block redundant inverse of the 12 lidar2img matrices (f64 GJ, pivot)
  if (tid < B_*N_) {
    int m = tid;
    double a[4][4], inv[4][4];
    for (int r=0;r<4;r++) for (int j=0;j<4;j++){
      a[r][j] = (double)l2i[m*16+r*4+j];
      inv[r][j] = (r==j)?1.0:0.0;
    }
    for (int k=0;k<4;k++){
      int pv=k; double mx=fabs(a[k][k]);
      for (int r=k+1;r<4;r++){ double v=fabs(a[r][k]); if (v>mx){mx=v;pv=r;} }
      if (pv!=k){
        for (int j=0;j<4;j++){
          double t=a[k][j]; a[k][j]=a[pv][j]; a[pv][j]=t;
          t=inv[k][j]; inv[k][j]=inv[pv][j]; inv[pv][j]=t;
        }
      }
      double pi = 1.0/a[k][k];
      for (int j=0;j<4;j++){ a[k][j]*=pi; inv[k][j]*=pi; }
      for (int r=0;r<4;r++) if (r!=k){
        double f=a[r][k];
        for (int j=0;j<4;j++){ a[r][j]-=f*a[k][j]; inv[r][j]-=f*inv[k][j]; }
      }
    }
    for (int r=0;r<4;r++) for (int j=0;j<4;j++)
      sinv[m*16+r*4+j] = (float)inv[r][j];
  }
  __syncthreads();

  // geometry (identical math to R8/R10; iv from LDS)
  int b  = p / P_PER_B;
  int r  = p - b*P_PER_B;
  int n  = r / (D_*FH*FW);
  int r2 = r - n*(D_*FH*FW);
  int d  = r2 / (FH*FW);
  int r3 = r2 - d*(FH*FW);
  int h  = r3 / FW;
  int w  = r3 - h*FW;
  int bn = b*N_ + n;

  float xw = (float)((double)w * (703.0/87.0));    // np.linspace in f64, rounded
  float yh = (float)((double)h * (255.0/31.0));
  float dd = (float)(d + 1);                       // ds = 1..59

  float t0 = itrans[bn*3+0], t1 = itrans[bn*3+1], t2 = itrans[bn*3+2];
  float s  = iscale[bn];

  float px = xw + t0, py = yh + t1, pd = dd + t2;
  float x0 = px / s, x1 = py / s;
  float p0 = x0*pd, p1 = x1*pd, p2 = pd;

  const float* iv = &sinv[bn*16];
  float gx = ((iv[0]*p0 + iv[1]*p1) + iv[2]*p2)  + iv[3]*1.0f;
  float gy = ((iv[4]*p0 + iv[5]*p1) + iv[6]*p2)  + iv[7]*1.0f;
  float gz = ((iv[8]*p0 + iv[9]*p1) + iv[10]*p2) + iv[11]*1.0f;

  int vx = (int)((gx + 54.0f) / 0.3f);             // trunc == astype(int32)
  int vy = (int)((gy + 54.0f) / 0.3f);
  int vz = (int)((gz + 10.0f) / 20.0f);

  bool ok = (vx>=0) & (vx<NX) & (vy>=0) & (vy<NY) & (vz>=0) & (vz<1);
  int code = ok ? (b*NCELL + vx*NY + vy) : -1;
  g_code[p] = code;

  int lane = tid & 63;
  int prev = __shfl_up(code, 1);
  bool leader = (lane == 0) || (code != prev);
  unsigned long long m = __ballot(leader);
  if (leader && code >= 0) {
    unsigned long long above = (lane < 63) ? (m >> (lane+1)) : 0ULL;
    int len = above ? __ffsll(above) : (64 - lane);
    atomicAdd(&g_cnt[code], len);
  }
}

// ---- 2) unordered segment allocation + classification (replaces the scans).
// Wave prefix-sum of counts; ONE g_total atomic per wave; packed list entries.
__global__ void __launch_bounds__(1024) k_alloc() {
  int t = threadIdx.x, bid = blockIdx.x;
  int i = bid*1024 + t;
  bool inb = (i < NC);
  int len = inb ? g_cnt[i] : 0;
  int lane = t & 63;

  int pre = len;                                   // wave-inclusive prefix
  #pragma unroll
  for (int off=1; off<64; off<<=1) {
    int x = __shfl_up(pre, off);
    if (lane >= off) pre += x;
  }
  int wtot = __shfl(pre, 63);
  int wbase = 0;
  if (lane == 63 && wtot > 0) wbase = atomicAdd(&g_total, wtot);
  wbase = __shfl(wbase, 63);
  int base = wbase + pre - len;                    // exclusive within wave
  if (inb && len > 0) g_cur[i] = base;

  bool isS = inb && (len > 0) && (len <= SMAX);
  unsigned long long m = __ballot(isS);
  if (m) {
    int ldr = __ffsll((long long)m) - 1;
    int cbase = 0;
    if (lane == ldr) cbase = atomicAdd(&g_nS, (int)__popcll(m));
    cbase = __shfl(cbase, ldr);
    if (isS) {
      int rank = __popcll(m & ((1ULL << lane) - 1ULL));
      g_cellS[cbase + rank] = make_int2(i | (len << 18), base);
    }
  }
  if (inb && len > SMAX) {
    int nch = (len + CHK - 1) / CHK;
    int cb = atomicAdd(&g_nB, nch);
    int sole = (nch == 1) ? 1 : 0;
    for (int k = 0; k < nch; ++k) {
      int clen = min(CHK, len - k*CHK);
      g_chunkB[cb + k] = make_int2(i | (clen << 18) | (sole << 30), base + k*CHK);
    }
  }
}

// ---- 3) fill cell-sorted point list + self-clean cnt/nS/nB/total
__global__ void k_fill() {
  int gid = blockIdx.x*256 + threadIdx.x;          // grid exact: NPTS/256
  if (gid < NCP/4) ((int4*)g_cnt)[gid] = make_int4(0,0,0,0);
  if (gid == 0) { g_nS2 = g_nS; g_nB2 = g_nB; g_nS = 0; g_nB = 0; g_total = 0; }

  int code = g_code[gid];
  int lane = threadIdx.x & 63;
  int prev = __shfl_up(code, 1);
  bool leader = (lane == 0) || (code != prev);
  unsigned long long m = __ballot(leader);
  unsigned long long mask_le = (lane==63) ? ~0ULL : ((1ULL << (lane+1)) - 1ULL);
  int leaderLane = 63 - __clzll(m & mask_le);
  int pos0 = 0;
  if (leader && code >= 0) {
    unsigned long long above = (lane < 63) ? (m >> (lane+1)) : 0ULL;
    int len = above ? __ffsll(above) : (64 - lane);
    pos0 = atomicAdd(&g_cur[code], len);
  }
  pos0 = __shfl(pos0, leaderLane);
  if (code >= 0) g_plist[pos0 + (lane - leaderLane)] = gid;
}

// ---- 4) gather: cell-per-worker, 8-deep plist->feats prefetch in both modes
__global__ void __launch_bounds__(256) k_gather(const float* __restrict__ feats,
                                                float* __restrict__ out) {
  const float4* f4 = (const float4*)feats;
  if (blockIdx.x < BBLK) {
    // wave-mode: one 64-lane wave per <=CHK chunk (3 pts x 20 ch-groups)
    int nB = g_nB2;
    int lane = threadIdx.x & 63;
    int wid = blockIdx.x*4 + (threadIdx.x >> 6);
    int grp = lane/20;
    int c4 = lane - grp*20;
    bool act = lane < 60;
    for (int it = wid; it < nB; it += BBLK*4) {
      int2 e = g_chunkB[it];
      int c    = e.x & 0x3FFFF;
      int clen = (e.x >> 18) & 0x7F;
      int sole = (e.x >> 30) & 1;
      int s0 = e.y;
      int s1 = s0 + clen;
      float ax=0.f, ay=0.f, az=0.f, aw=0.f;
      if (act) {
        int j = s0 + grp;
        for (; j + 21 < s1; j += 24) {             // 8 pts per group in flight
          int p[8];
          #pragma unroll
          for (int k=0;k<8;++k) p[k] = g_plist[j + 3*k];
          float4 v[8];
          #pragma unroll
          for (int k=0;k<8;++k) v[k] = f4[(size_t)p[k]*20 + c4];
          #pragma unroll
          for (int k=0;k<8;++k) { ax+=v[k].x; ay+=v[k].y; az+=v[k].z; aw+=v[k].w; }
        }
        for (; j < s1; j += 3) {
          int p = g_plist[j];
          float4 v = f4[(size_t)p*20 + c4];
          ax+=v.x; ay+=v.y; az+=v.z; aw+=v.w;
        }
      }
      float bx=__shfl(ax,c4+20), by=__shfl(ay,c4+20), bz=__shfl(az,c4+20), bw=__shfl(aw,c4+20);
      float cx=__shfl(ax,c4+40), cy=__shfl(ay,c4+40), cz=__shfl(az,c4+40), cw=__shfl(aw,c4+40);
      if (lane < 20) {
        ax += bx + cx; ay += by + cy; az += bz + cz; aw += bw + cw;
        int b = c / NCELL;
        int xy = c - b*NCELL;
        float* dst = out + (size_t)(b*C_ + c4*4)*NCELL + xy;
        if (sole) {
          dst[0]       = ax;
          dst[NCELL]   = ay;
          dst[2*NCELL] = az;
          dst[3*NCELL] = aw;
        } else {                                   // dst zeroed by k_geomz
          atomicAdd(dst,         ax);
          atomicAdd(dst+NCELL,   ay);
          atomicAdd(dst+2*NCELL, az);
          atomicAdd(dst+3*NCELL, aw);
        }
      }
    }
  } else {
    // thread-mode: thread per (small cell, c4); branch-free 8-batches
    int nS = g_nS2;
    int tot = nS*20;
    for (int i = (blockIdx.x - BBLK)*256 + threadIdx.x; i < tot; i += SBLK*256) {
      int ci = i/20;
      int c4 = i - ci*20;
      int2 e = g_cellS[ci];
      int c   = e.x & 0x3FFFF;
      int len = (e.x >> 18) & 0x7F;                // 1..SMAX
      int o0  = e.y;
      float ax=0.f, ay=0.f, az=0.f, aw=0.f;
      int nb = (len + 7) >> 3;                     // 1..4 batches
      for (int bi = 0; bi < nb; ++bi) {
        int base = o0 + bi*8;
        int rem = len - bi*8;                      // >0
        int p[8];
        #pragma unroll
        for (int k=0;k<8;++k) p[k] = g_plist[min(base+k, NPTS-1)];
        float4 v[8];
        #pragma unroll
        for (int k=0;k<8;++k) {
          int q = min(max(p[k],0), NPTS-1);        // clamp stale tails in-bounds
          v[k] = f4[(size_t)q*20 + c4];
        }
        #pragma unroll
        for (int k=0;k<8;++k) {
          float sel = (k < rem) ? 1.f : 0.f;       // exact: adds 0.0 terms
          ax = fmaf(sel, v[k].x, ax);
          ay = fmaf(sel, v[k].y, ay);
          az = fmaf(sel, v[k].z, az);
          aw = fmaf(sel, v[k].w, aw);
        }
      }
      int b = c / NCELL;
      int xy = c - b*NCELL;
      float* dst = out + (size_t)(b*C_ + c4*4)*NCELL + xy;
      dst[0]       = ax;
      dst[NCELL]   = ay;
      dst[2*NCELL] = az;
      dst[3*NCELL] = aw;
    }
  }
}

extern "C" void kernel_launch(void* const* d_in, const int* in_sizes, int n_in,
                              void* d_out, int out_size, void* d_ws, size_t ws_size,
                              hipStream_t stream) {
  const float* feats  = (const float*)d_in[0];
  const float* itrans = (const float*)d_in[1];
  const float* iscale = (const float*)d_in[2];
  const float* l2i    = (const float*)d_in[3];
  float* out = (float*)d_out;

  k_geomz<<<NPTS/256, 256, 0, stream>>>(itrans, iscale, l2i, out); // 7,788 blocks
  k_alloc<<<NBLK, 1024, 0, stream>>>();                            // 254 blocks
  k_fill<<<NPTS/256, 256, 0, stream>>>();                          // 7,788 blocks
  k_gather<<<TOTBLK, 256, 0, stream>>>(feats, out);                // 2,048 blocks
}

// Round 12
// 125.497 us; speedup vs baseline: 4.6522x; 1.0170x over previous
//
#include <hip/hip_runtime.h>
#include <math.h>

#define B_ 2
#define N_ 6
#define D_ 59
#define FH 32
#define FW 88
#define C_ 80
#define NX 360
#define NY 360
#define P_PER_B (N_*D_*FH*FW)     // 996,864
#define NPTS (B_*P_PER_B)         // 1,993,728 = 7788*256
#define NCELL (NX*NY)             // 129,600
#define NC (B_*NCELL)             // 259,200 cells
#define NBLK 254
#define NCP (NBLK*1024)           // 260,096
#define OUT4 (B_*C_*NCELL/4)      // 5,184,000 float4 in out
#define SMAX 32                   // cells <= SMAX points -> thread-mode
#define CHK 96                    // points per wave-chunk (divisible by 3)
#define MAXCHK (NC/4 + NPTS/CHK)
#define TOTBLK 2048
#define NWAVES (TOTBLK*256/64)    // 8192

// Static device scratch. Self-cleaning invariant: g_cnt/g_nS/g_nB/g_total are
// zero at every launch entry (BSS zero-init for launch #1; k_alloc re-zeroes
// cnt after its last read, k_fill re-zeroes the counters after snapshot).
__device__ int   g_code[NPTS];
__device__ __align__(16) int g_cnt[NCP];
__device__ int   g_cur[NC];
__device__ __align__(16) int g_plist[NPTS];
__device__ int   g_total;
__device__ int   g_nS, g_nB;       // appended by alloc; zeroed by fill
__device__ int   g_nS2, g_nB2;     // snapshots read by gather
__device__ int2  g_cellS[NC];      // {cell | len<<18, o0}
__device__ int2  g_chunkB[MAXCHK]; // {cell | clen<<18 | sole<<30, s0}

// ---- 1) geom fused with out-zero + per-block redundant matrix inverse
__global__ void k_geomz(const float* __restrict__ itrans,
                        const float* __restrict__ iscale,
                        const float* __restrict__ l2i,
                        float* __restrict__ out) {
#pragma clang fp contract(off)
  __shared__ float sinv[B_*N_*16];
  int tid = threadIdx.x;
  int p = blockIdx.x*256 + tid;                    // grid exact: NPTS/256

  // out-zero (fire-and-forget stores; overlap the inverse + geom below)
  const float4 z4 = make_float4(0.f,0.f,0.f,0.f);
  ((float4*)out)[p] = z4;
  ((float4*)out)[p + NPTS] = z4;
  {
    int u = p + 2*NPTS;
    if (u < OUT4) ((float4*)out)[u] = z4;
  }

  // per-block redundant inverse of the 12 lidar2img matrices (f64 GJ, pivot)
  if (tid < B_*N_) {
    int m = tid;
    double a[4][4], inv[4][4];
    for (int r=0;r<4;r++) for (int j=0;j<4;j++){
      a[r][j] = (double)l2i[m*16+r*4+j];
      inv[r][j] = (r==j)?1.0:0.0;
    }
    for (int k=0;k<4;k++){
      int pv=k; double mx=fabs(a[k][k]);
      for (int r=k+1;r<4;r++){ double v=fabs(a[r][k]); if (v>mx){mx=v;pv=r;} }
      if (pv!=k){
        for (int j=0;j<4;j++){
          double t=a[k][j]; a[k][j]=a[pv][j]; a[pv][j]=t;
          t=inv[k][j]; inv[k][j]=inv[pv][j]; inv[pv][j]=t;
        }
      }
      double pi = 1.0/a[k][k];
      for (int j=0;j<4;j++){ a[k][j]*=pi; inv[k][j]*=pi; }
      for (int r=0;r<4;r++) if (r!=k){
        double f=a[r][k];
        for (int j=0;j<4;j++){ a[r][j]-=f*a[k][j]; inv[r][j]-=f*inv[k][j]; }
      }
    }
    for (int r=0;r<4;r++) for (int j=0;j<4;j++)
      sinv[m*16+r*4+j] = (float)inv[r][j];
  }
  __syncthreads();

  // geometry (identical math to R8/R10/R11; iv from LDS)
  int b  = p / P_PER_B;
  int r  = p - b*P_PER_B;
  int n  = r / (D_*FH*FW);
  int r2 = r - n*(D_*FH*FW);
  int d  = r2 / (FH*FW);
  int r3 = r2 - d*(FH*FW);
  int h  = r3 / FW;
  int w  = r3 - h*FW;
  int bn = b*N_ + n;

  float xw = (float)((double)w * (703.0/87.0));    // np.linspace in f64, rounded
  float yh = (float)((double)h * (255.0/31.0));
  float dd = (float)(d + 1);                       // ds = 1..59

  float t0 = itrans[bn*3+0], t1 = itrans[bn*3+1], t2 = itrans[bn*3+2];
  float s  = iscale[bn];

  float px = xw + t0, py = yh + t1, pd = dd + t2;
  float x0 = px / s, x1 = py / s;
  float p0 = x0*pd, p1 = x1*pd, p2 = pd;

  const float* iv = &sinv[bn*16];
  float gx = ((iv[0]*p0 + iv[1]*p1) + iv[2]*p2)  + iv[3]*1.0f;
  float gy = ((iv[4]*p0 + iv[5]*p1) + iv[6]*p2)  + iv[7]*1.0f;
  float gz = ((iv[8]*p0 + iv[9]*p1) + iv[10]*p2) + iv[11]*1.0f;

  int vx = (int)((gx + 54.0f) / 0.3f);             // trunc == astype(int32)
  int vy = (int)((gy + 54.0f) / 0.3f);
  int vz = (int)((gz + 10.0f) / 20.0f);

  bool ok = (vx>=0) & (vx<NX) & (vy>=0) & (vy<NY) & (vz>=0) & (vz<1);
  int code = ok ? (b*NCELL + vx*NY + vy) : -1;
  g_code[p] = code;

  int lane = tid & 63;
  int prev = __shfl_up(code, 1);
  bool leader = (lane == 0) || (code != prev);
  unsigned long long m = __ballot(leader);
  if (leader && code >= 0) {
    unsigned long long above = (lane < 63) ? (m >> (lane+1)) : 0ULL;
    int len = above ? __ffsll(above) : (64 - lane);
    atomicAdd(&g_cnt[code], len);
  }
}

// ---- 2) unordered segment allocation + classification; self-cleans cnt
__global__ void __launch_bounds__(1024) k_alloc() {
  int t = threadIdx.x, bid = blockIdx.x;
  int i = bid*1024 + t;
  bool inb = (i < NC);
  int len = inb ? g_cnt[i] : 0;
  if (inb && len) g_cnt[i] = 0;                    // self-clean for next launch
  int lane = t & 63;

  int pre = len;                                   // wave-inclusive prefix
  #pragma unroll
  for (int off=1; off<64; off<<=1) {
    int x = __shfl_up(pre, off);
    if (lane >= off) pre += x;
  }
  int wtot = __shfl(pre, 63);
  int wbase = 0;
  if (lane == 63 && wtot > 0) wbase = atomicAdd(&g_total, wtot);
  wbase = __shfl(wbase, 63);
  int base = wbase + pre - len;                    // exclusive within wave
  if (inb && len > 0) g_cur[i] = base;

  bool isS = inb && (len > 0) && (len <= SMAX);
  unsigned long long m = __ballot(isS);
  if (m) {
    int ldr = __ffsll((long long)m) - 1;
    int cbase = 0;
    if (lane == ldr) cbase = atomicAdd(&g_nS, (int)__popcll(m));
    cbase = __shfl(cbase, ldr);
    if (isS) {
      int rank = __popcll(m & ((1ULL << lane) - 1ULL));
      g_cellS[cbase + rank] = make_int2(i | (len << 18), base);
    }
  }
  if (inb && len > SMAX) {
    int nch = (len + CHK - 1) / CHK;
    int cb = atomicAdd(&g_nB, nch);
    int sole = (nch == 1) ? 1 : 0;
    for (int k = 0; k < nch; ++k) {
      int clen = min(CHK, len - k*CHK);
      g_chunkB[cb + k] = make_int2(i | (clen << 18) | (sole << 30), base + k*CHK);
    }
  }
}

// ---- 3) fill cell-sorted point list + snapshot/clean counters
__global__ void k_fill() {
  int gid = blockIdx.x*256 + threadIdx.x;          // grid exact: NPTS/256
  if (gid == 0) { g_nS2 = g_nS; g_nB2 = g_nB; g_nS = 0; g_nB = 0; g_total = 0; }

  int code = g_code[gid];
  int lane = threadIdx.x & 63;
  int prev = __shfl_up(code, 1);
  bool leader = (lane == 0) || (code != prev);
  unsigned long long m = __ballot(leader);
  unsigned long long mask_le = (lane==63) ? ~0ULL : ((1ULL << (lane+1)) - 1ULL);
  int leaderLane = 63 - __clzll(m & mask_le);
  int pos0 = 0;
  if (leader && code >= 0) {
    unsigned long long above = (lane < 63) ? (m >> (lane+1)) : 0ULL;
    int len = above ? __ffsll(above) : (64 - lane);
    pos0 = atomicAdd(&g_cur[code], len);
  }
  pos0 = __shfl(pos0, leaderLane);
  if (code >= 0) g_plist[pos0 + (lane - leaderLane)] = gid;
}

// ---- 4) gather, unified: ALL 8192 waves grid-stride the chunk list
// (wave-mode), then fall through to small-cell items (thread-mode).
__global__ void __launch_bounds__(256) k_gather(const float* __restrict__ feats,
                                                float* __restrict__ out) {
  const float4* f4 = (const float4*)feats;
  int gtid = blockIdx.x*256 + threadIdx.x;
  int lane = threadIdx.x & 63;

  // ---- wave-mode: one 64-lane wave per <=CHK chunk (3 pts x 20 ch-groups)
  {
    int nB = g_nB2;
    int wid = gtid >> 6;
    int grp = lane/20;
    int c4 = lane - grp*20;
    bool act = lane < 60;
    for (int it = wid; it < nB; it += NWAVES) {
      int2 e = g_chunkB[it];
      int c    = e.x & 0x3FFFF;
      int clen = (e.x >> 18) & 0x7F;
      int sole = (e.x >> 30) & 1;
      int s0 = e.y;
      int s1 = s0 + clen;
      float ax=0.f, ay=0.f, az=0.f, aw=0.f;
      if (act) {
        #pragma unroll 1
        for (int rr=0; rr<4; ++rr) {               // 4 rounds x 8-deep, branch-free
          int j0 = s0 + grp + 24*rr;
          if (j0 >= s1) break;
          int p[8];
          #pragma unroll
          for (int k=0;k<8;++k) p[k] = g_plist[min(j0 + 3*k, NPTS-1)];
          float4 v[8];
          #pragma unroll
          for (int k=0;k<8;++k) v[k] = f4[(size_t)min(max(p[k],0),NPTS-1)*20 + c4];
          #pragma unroll
          for (int k=0;k<8;++k) {
            float sel = (j0 + 3*k < s1) ? 1.f : 0.f;   // exact: adds 0.0 terms
            ax = fmaf(sel, v[k].x, ax);
            ay = fmaf(sel, v[k].y, ay);
            az = fmaf(sel, v[k].z, az);
            aw = fmaf(sel, v[k].w, aw);
          }
        }
      }
      float bx=__shfl(ax,c4+20), by=__shfl(ay,c4+20), bz=__shfl(az,c4+20), bw=__shfl(aw,c4+20);
      float cx=__shfl(ax,c4+40), cy=__shfl(ay,c4+40), cz=__shfl(az,c4+40), cw=__shfl(aw,c4+40);
      if (lane < 20) {
        ax += bx + cx; ay += by + cy; az += bz + cz; aw += bw + cw;
        int b = c / NCELL;
        int xy = c - b*NCELL;
        float* dst = out + (size_t)(b*C_ + c4*4)*NCELL + xy;
        if (sole) {
          dst[0]       = ax;
          dst[NCELL]   = ay;
          dst[2*NCELL] = az;
          dst[3*NCELL] = aw;
        } else {                                   // dst zeroed by k_geomz
          atomicAdd(dst,         ax);
          atomicAdd(dst+NCELL,   ay);
          atomicAdd(dst+2*NCELL, az);
          atomicAdd(dst+3*NCELL, aw);
        }
      }
    }
  }

  // ---- thread-mode: thread per (small cell, c4); branch-free 8-batches
  {
    int nS = g_nS2;
    int tot = nS*20;
    for (int i = gtid; i < tot; i += TOTBLK*256) {
      int ci = i/20;
      int c4 = i - ci*20;
      int2 e = g_cellS[ci];
      int c   = e.x & 0x3FFFF;
      int len = (e.x >> 18) & 0x7F;                // 1..SMAX
      int o0  = e.y;
      float ax=0.f, ay=0.f, az=0.f, aw=0.f;
      int nb = (len + 7) >> 3;                     // 1..4 batches
      for (int bi = 0; bi < nb; ++bi) {
        int base = o0 + bi*8;
        int rem = len - bi*8;                      // >0
        int p[8];
        #pragma unroll
        for (int k=0;k<8;++k) p[k] = g_plist[min(base+k, NPTS-1)];
        float4 v[8];
        #pragma unroll
        for (int k=0;k<8;++k) {
          int q = min(max(p[k],0), NPTS-1);        // clamp stale tails in-bounds
          v[k] = f4[(size_t)q*20 + c4];
        }
        #pragma unroll
        for (int k=0;k<8;++k) {
          float sel = (k < rem) ? 1.f : 0.f;       // exact: adds 0.0 terms
          ax = fmaf(sel, v[k].x, ax);
          ay = fmaf(sel, v[k].y, ay);
          az = fmaf(sel, v[k].z, az);
          aw = fmaf(sel, v[k].w, aw);
        }
      }
      int b = c / NCELL;
      int xy = c - b*NCELL;
      float* dst = out + (size_t)(b*C_ + c4*4)*NCELL + xy;
      dst[0]       = ax;
      dst[NCELL]   = ay;
      dst[2*NCELL] = az;
      dst[3*NCELL] = aw;
    }
  }
}

extern "C" void kernel_launch(void* const* d_in, const int* in_sizes, int n_in,
                              void* d_out, int out_size, void* d_ws, size_t ws_size,
                              hipStream_t stream) {
  const float* feats  = (const float*)d_in[0];
  const float* itrans = (const float*)d_in[1];
  const float* iscale = (const float*)d_in[2];
  const float* l2i    = (const float*)d_in[3];
  float* out = (float*)d_out;

  k_geomz<<<NPTS/256, 256, 0, stream>>>(itrans, iscale, l2i, out); // 7,788 blocks
  k_alloc<<<NBLK, 1024, 0, stream>>>();                            // 254 blocks
  k_fill<<<NPTS/256, 256, 0, stream>>>();                          // 7,788 blocks
  k_gather<<<TOTBLK, 256, 0, stream>>>(feats, out);                // 2,048 blocks
}